// Round 1
// baseline (241.814 us; speedup 1.0000x reference)
//
#include <hip/hip_runtime.h>
#include <hip/hip_bf16.h>

#define B_  16
#define C_  64
#define HW  4096   // 64*64
#define KP  1024   // pooled positions (32*32)
#define C8  8
#define C2  32

// ---------------------------------------------------------------------------
// Kernel A: fused 1x1 conv (40 out channels = phi(8) ++ g(32)) + 2x2 maxpool.
// Block = 256 threads = 4 image rows (one batch, rowgroup rg covers rows
// 4rg..4rg+3 -> pooled rows 2rg..2rg+1). x is read exactly once.
// Outputs TRANSPOSED for kernel B staging: phi_t[B][KP][8], g_t[B][KP][32].
// ---------------------------------------------------------------------------
__global__ __launch_bounds__(256) void convpool_kernel(
    const float* __restrict__ x,
    const float* __restrict__ w_phi,
    const float* __restrict__ w_g,
    float* __restrict__ phi_t,
    float* __restrict__ g_t)
{
    __shared__ float conv_lds[256 * 41];   // [pos][40] padded to 41 (bank-stride 9)
    const int bi = blockIdx.x;
    const int b  = bi >> 4;
    const int rg = bi & 15;
    const int t  = threadIdx.x;

    const int q = rg * 256 + t;            // global pixel index within image
    const float* xb = x + (size_t)b * C_ * HW + q;

    float acc[40];
    #pragma unroll
    for (int oc = 0; oc < 40; ++oc) acc[oc] = 0.f;

    #pragma unroll 2
    for (int c = 0; c < C_; ++c) {
        const float xv = xb[(size_t)c * HW];          // coalesced across lanes
        #pragma unroll
        for (int oc = 0; oc < 8; ++oc)  acc[oc]     += w_phi[oc * C_ + c] * xv; // scalar loads
        #pragma unroll
        for (int oc = 0; oc < 32; ++oc) acc[8 + oc] += w_g[oc * C_ + c] * xv;
    }

    #pragma unroll
    for (int oc = 0; oc < 40; ++oc) conv_lds[t * 41 + oc] = acc[oc];
    __syncthreads();

    // pool phase: 40 channels x 64 pooled positions per block
    for (int wi = t; wi < 40 * 64; wi += 256) {
        const int oc = wi >> 6;
        const int kl = wi & 63;
        const int pr = kl >> 5, pc = kl & 31;
        const int i00 = (2 * pr) * 64 + 2 * pc;       // local pixel idx of window TL
        const float v0 = conv_lds[(i00)      * 41 + oc];
        const float v1 = conv_lds[(i00 + 1)  * 41 + oc];
        const float v2 = conv_lds[(i00 + 64) * 41 + oc];
        const float v3 = conv_lds[(i00 + 65) * 41 + oc];
        const float v  = fmaxf(fmaxf(v0, v1), fmaxf(v2, v3));
        const int kg = (2 * rg + pr) * 32 + pc;       // global pooled index 0..1023
        if (oc < 8) phi_t[((size_t)b * KP + kg) * 8  + oc]       = v;
        else        g_t  [((size_t)b * KP + kg) * 32 + (oc - 8)] = v;
    }
}

// ---------------------------------------------------------------------------
// Kernel B: fused theta-conv + scores + softmax + attn*g + w_o conv + residual.
// Block = 256 threads = 256 queries (16 blocks per batch). 1 query per thread.
// phi (all 1024 keys, 32KB) resident in LDS; g streamed in 4 chunks of 256
// keys (32KB). Per-k LDS reads are wave-uniform -> bank broadcast, no
// conflicts. Two-pass softmax (max then exp-accumulate): branch-free.
// ---------------------------------------------------------------------------
__global__ __launch_bounds__(256) void attn_kernel(
    const float* __restrict__ x,
    const float* __restrict__ w_theta,
    const float* __restrict__ w_o,
    const float* __restrict__ gamma_p,
    const float* __restrict__ phi_t,
    const float* __restrict__ g_t,
    float* __restrict__ out)
{
    __shared__ float phi_s[KP * 8];     // 32 KB, [k][8]
    __shared__ float g_s[256 * 32];     // 32 KB, [k_local][32]

    const int bi = blockIdx.x;
    const int b  = bi >> 4;
    const int qb = bi & 15;
    const int t  = threadIdx.x;
    const int q  = qb * 256 + t;

    // stage full phi for this batch (8192 floats)
    {
        const float4* src = (const float4*)(phi_t + (size_t)b * KP * 8);
        float4* dst = (float4*)phi_s;
        #pragma unroll
        for (int i = 0; i < 8; ++i) dst[t + i * 256] = src[t + i * 256];
    }
    // stage g chunk 0 (8192 floats)
    {
        const float4* src = (const float4*)(g_t + (size_t)b * KP * 32);
        float4* dst = (float4*)g_s;
        #pragma unroll
        for (int i = 0; i < 8; ++i) dst[t + i * 256] = src[t + i * 256];
    }

    // theta for this thread's query (8 channels)
    const float* xb = x + (size_t)b * C_ * HW + q;
    float th[8];
    #pragma unroll
    for (int c = 0; c < 8; ++c) th[c] = 0.f;
    #pragma unroll 2
    for (int ch = 0; ch < C_; ++ch) {
        const float xv = xb[(size_t)ch * HW];         // coalesced across lanes
        #pragma unroll
        for (int c = 0; c < 8; ++c) th[c] += w_theta[c * C_ + ch] * xv;
    }
    __syncthreads();

    // pass 1: row max over all 1024 keys
    float m = -1e30f;
    #pragma unroll 4
    for (int k = 0; k < KP; ++k) {
        const float4 p0 = *(const float4*)&phi_s[k * 8];
        const float4 p1 = *(const float4*)&phi_s[k * 8 + 4];
        const float s = th[0]*p0.x + th[1]*p0.y + th[2]*p0.z + th[3]*p0.w
                      + th[4]*p1.x + th[5]*p1.y + th[6]*p1.z + th[7]*p1.w;
        m = fmaxf(m, s);
    }

    // pass 2: exp + accumulate attn*g, streaming g in 4 chunks
    float4 acc[8];
    #pragma unroll
    for (int j = 0; j < 8; ++j) acc[j] = make_float4(0.f, 0.f, 0.f, 0.f);
    float l = 0.f;

    for (int chunk = 0; chunk < 4; ++chunk) {
        if (chunk > 0) {
            __syncthreads();   // everyone done reading previous g chunk
            const float4* src = (const float4*)(g_t + ((size_t)b * KP + chunk * 256) * 32);
            float4* dst = (float4*)g_s;
            #pragma unroll
            for (int i = 0; i < 8; ++i) dst[t + i * 256] = src[t + i * 256];
            __syncthreads();
        }
        const int kb = chunk * 256;
        #pragma unroll 2
        for (int kl = 0; kl < 256; ++kl) {
            const int k = kb + kl;
            const float4 p0 = *(const float4*)&phi_s[k * 8];
            const float4 p1 = *(const float4*)&phi_s[k * 8 + 4];
            const float s = th[0]*p0.x + th[1]*p0.y + th[2]*p0.z + th[3]*p0.w
                          + th[4]*p1.x + th[5]*p1.y + th[6]*p1.z + th[7]*p1.w;
            const float pe = __expf(s - m);
            l += pe;
            const float4* gv = (const float4*)&g_s[kl * 32];
            #pragma unroll
            for (int j = 0; j < 8; ++j) {
                const float4 g4 = gv[j];
                acc[j].x += pe * g4.x;
                acc[j].y += pe * g4.y;
                acc[j].z += pe * g4.z;
                acc[j].w += pe * g4.w;
            }
        }
    }

    // normalize
    const float inv = 1.0f / l;
    float an[32];
    #pragma unroll
    for (int j = 0; j < 8; ++j) {
        an[4*j + 0] = acc[j].x * inv;
        an[4*j + 1] = acc[j].y * inv;
        an[4*j + 2] = acc[j].z * inv;
        an[4*j + 3] = acc[j].w * inv;
    }

    // epilogue: out = x + gamma * (w_o @ attn_g)
    const float gam = gamma_p[0];
    float* ob = out + (size_t)b * C_ * HW + q;
    #pragma unroll 2
    for (int co = 0; co < C_; ++co) {
        float o = 0.f;
        #pragma unroll
        for (int j = 0; j < 32; ++j) o += w_o[co * 32 + j] * an[j];  // scalar loads
        ob[(size_t)co * HW] = xb[(size_t)co * HW] + gam * o;
    }
}

extern "C" void kernel_launch(void* const* d_in, const int* in_sizes, int n_in,
                              void* d_out, int out_size, void* d_ws, size_t ws_size,
                              hipStream_t stream) {
    const float* x       = (const float*)d_in[0];
    const float* w_theta = (const float*)d_in[1];
    const float* w_phi   = (const float*)d_in[2];
    const float* w_g     = (const float*)d_in[3];
    const float* w_o     = (const float*)d_in[4];
    const float* gamma   = (const float*)d_in[5];
    float* out = (float*)d_out;

    float* phi_t = (float*)d_ws;                 // B*KP*8  = 131072 floats (0.5 MB)
    float* g_t   = phi_t + (size_t)B_ * KP * 8;  // B*KP*32 = 524288 floats (2.0 MB)

    convpool_kernel<<<dim3(B_ * 16), dim3(256), 0, stream>>>(x, w_phi, w_g, phi_t, g_t);
    attn_kernel<<<dim3(B_ * 16), dim3(256), 0, stream>>>(x, w_theta, w_o, gamma,
                                                         phi_t, g_t, out);
}

// Round 2
// 47.578 us; speedup vs baseline: 5.0825x; 5.0825x over previous
//
#include <hip/hip_runtime.h>
#include <hip/hip_bf16.h>

#define B_  16
#define C_  64
#define HW  4096   // 64*64
#define KP  1024   // pooled positions (32*32)
#define LOG2E 1.44269504088896f

typedef short short8 __attribute__((ext_vector_type(8)));
typedef float floatx16 __attribute__((ext_vector_type(16)));

union Frag { uint4 u; short8 s; };

// ---- LDS layout (bytes) for attn kernel ----
#define PHI_OFF   0        // [1024][8] bf16 = 16384
#define ZERO_OFF  16384    // 16B zeros (hi-lane K-pad reads)
#define THETA_OFF 16400    // [256][8] bf16 = 4096
#define G_OFF     20496    // [32][1032] bf16 rows (2064B stride) = 66048
#define WO_OFF    86544    // [64][40] bf16 rows (80B stride) = 5120
#define ATTN_OFF  91664    // [256][36] f32 rows (144B stride) = 36864
#define LDS_BYTES 128528
#define G_ROW     2064
#define WO_ROW    80
#define ATTN_ROW  144

__device__ __forceinline__ unsigned cvt_pk_bf16(float lo, float hi) {
    unsigned r;
    asm("v_cvt_pk_bf16_f32 %0, %1, %2" : "=v"(r) : "v"(lo), "v"(hi));
    return r;
}
#define PLSWAP(a, b) asm("v_permlane32_swap_b32 %0, %1" : "+v"(a), "+v"(b))

// Build the two PV A-operand fragments (K=16 each) from 16 lane-local P values.
// p[r] = P[q = lane&31][key = (r&3) + 8*(r>>2) + 4*(lane>>5)] (within 32-key tile).
__device__ __forceinline__ void build_pfrags(const float* p, Frag& f0, Frag& f1) {
    unsigned u0 = cvt_pk_bf16(p[0], p[1]);
    unsigned u1 = cvt_pk_bf16(p[2], p[3]);
    unsigned u2 = cvt_pk_bf16(p[4], p[5]);
    unsigned u3 = cvt_pk_bf16(p[6], p[7]);
    PLSWAP(u0, u2);   // u0: keys(0,1)|(8,9)   u2: keys(4,5)|(12,13)
    PLSWAP(u1, u3);   // u1: keys(2,3)|(10,11) u3: keys(6,7)|(14,15)
    f0.u.x = u0; f0.u.y = u1; f0.u.z = u2; f0.u.w = u3;
    unsigned v0 = cvt_pk_bf16(p[8],  p[9]);
    unsigned v1 = cvt_pk_bf16(p[10], p[11]);
    unsigned v2 = cvt_pk_bf16(p[12], p[13]);
    unsigned v3 = cvt_pk_bf16(p[14], p[15]);
    PLSWAP(v0, v2);
    PLSWAP(v1, v3);
    f1.u.x = v0; f1.u.y = v1; f1.u.z = v2; f1.u.w = v3;
}

// ---------------------------------------------------------------------------
// Kernel A: fused 1x1 conv (40 oc = phi(8) ++ g(32)) + 2x2 maxpool.
// Outputs bf16: phi_b[B][1024][8], gT_b[B][32][1024] (g transposed).
// ---------------------------------------------------------------------------
__global__ __launch_bounds__(256) void convpool_kernel(
    const float* __restrict__ x,
    const float* __restrict__ w_phi,
    const float* __restrict__ w_g,
    __hip_bfloat16* __restrict__ phi_b,
    __hip_bfloat16* __restrict__ gT_b)
{
    __shared__ float conv_lds[256 * 41];
    const int bi = blockIdx.x;
    const int b  = bi >> 4;
    const int rg = bi & 15;
    const int t  = threadIdx.x;

    const int q = rg * 256 + t;
    const float* xb = x + (size_t)b * C_ * HW + q;

    float acc[40];
    #pragma unroll
    for (int oc = 0; oc < 40; ++oc) acc[oc] = 0.f;

    #pragma unroll 2
    for (int c = 0; c < C_; ++c) {
        const float xv = xb[(size_t)c * HW];
        #pragma unroll
        for (int oc = 0; oc < 8; ++oc)  acc[oc]     += w_phi[oc * C_ + c] * xv;
        #pragma unroll
        for (int oc = 0; oc < 32; ++oc) acc[8 + oc] += w_g[oc * C_ + c] * xv;
    }

    #pragma unroll
    for (int oc = 0; oc < 40; ++oc) conv_lds[t * 41 + oc] = acc[oc];
    __syncthreads();

    for (int wi = t; wi < 40 * 64; wi += 256) {
        const int oc = wi >> 6;
        const int kl = wi & 63;
        const int pr = kl >> 5, pc = kl & 31;
        const int i00 = (2 * pr) * 64 + 2 * pc;
        const float v0 = conv_lds[(i00)      * 41 + oc];
        const float v1 = conv_lds[(i00 + 1)  * 41 + oc];
        const float v2 = conv_lds[(i00 + 64) * 41 + oc];
        const float v3 = conv_lds[(i00 + 65) * 41 + oc];
        const float v  = fmaxf(fmaxf(v0, v1), fmaxf(v2, v3));
        const int kg = (2 * rg + pr) * 32 + pc;
        if (oc < 8) phi_b[((size_t)b * KP + kg) * 8 + oc] = __float2bfloat16(v);
        else        gT_b[((size_t)b * 32 + (oc - 8)) * KP + kg] = __float2bfloat16(v);
    }
}

// ---------------------------------------------------------------------------
// Kernel B: MFMA flash attention + w_o conv + residual.
// Grid 256 blocks (16/batch, 256 queries each), 256 threads = 4 waves.
// Wave w owns q-tiles [64w,64w+32) and [64w+32,64w+64).
// ---------------------------------------------------------------------------
__global__ __launch_bounds__(256, 1) void attn_kernel(
    const float* __restrict__ x,
    const float* __restrict__ w_theta,
    const float* __restrict__ w_o,
    const float* __restrict__ gamma_p,
    const __hip_bfloat16* __restrict__ phi_b,
    const __hip_bfloat16* __restrict__ gT_b,
    float* __restrict__ out)
{
    __shared__ __align__(16) char lds[LDS_BYTES];
    const int t   = threadIdx.x;
    const int b   = blockIdx.x >> 4;
    const int qb0 = (blockIdx.x & 15) * 256;

    // ---- stage phi: 1024 granules of 16B ----
    {
        const uint4* src = (const uint4*)phi_b + (size_t)b * KP;
        uint4* dst = (uint4*)(lds + PHI_OFF);
        #pragma unroll
        for (int i = 0; i < 4; ++i) dst[t + 256 * i] = src[t + 256 * i];
    }
    if (t == 0) { uint4 z = {0u,0u,0u,0u}; *(uint4*)(lds + ZERO_OFF) = z; }
    // ---- stage g transposed rows with +16B pad ----
    {
        const uint4* src = (const uint4*)gT_b + (size_t)b * 32 * 128;
        #pragma unroll
        for (int i = 0; i < 16; ++i) {
            const int gi = t + 256 * i;
            const int c = gi >> 7, kk = gi & 127;
            *(uint4*)(lds + G_OFF + c * G_ROW + kk * 16) = src[gi];
        }
    }
    // ---- stage w_o as bf16 padded rows ----
    {
        const int co = t >> 2, part = t & 3;
        const float4* wsrc = (const float4*)(w_o + co * 32 + part * 8);
        const float4 f0 = wsrc[0], f1 = wsrc[1];
        uint4 u;
        u.x = cvt_pk_bf16(f0.x, f0.y); u.y = cvt_pk_bf16(f0.z, f0.w);
        u.z = cvt_pk_bf16(f1.x, f1.y); u.w = cvt_pk_bf16(f1.z, f1.w);
        *(uint4*)(lds + WO_OFF + co * WO_ROW + part * 16) = u;
    }
    // ---- theta (x log2e) for q = qb0 + t ----
    {
        const float* xb = x + (size_t)b * C_ * HW + qb0 + t;
        float th[8];
        #pragma unroll
        for (int j = 0; j < 8; ++j) th[j] = 0.f;
        #pragma unroll 4
        for (int c = 0; c < C_; ++c) {
            const float xv = xb[(size_t)c * HW];
            #pragma unroll
            for (int j = 0; j < 8; ++j) th[j] += w_theta[j * C_ + c] * xv;
        }
        uint4 u;
        u.x = cvt_pk_bf16(th[0] * LOG2E, th[1] * LOG2E);
        u.y = cvt_pk_bf16(th[2] * LOG2E, th[3] * LOG2E);
        u.z = cvt_pk_bf16(th[4] * LOG2E, th[5] * LOG2E);
        u.w = cvt_pk_bf16(th[6] * LOG2E, th[7] * LOG2E);
        *(uint4*)(lds + THETA_OFF + t * 16) = u;
    }
    __syncthreads();

    const int lane = t & 63;
    const int wv   = t >> 6;
    const int hi   = lane >> 5;
    const int ln   = lane & 31;
    const int qt0  = wv * 64, qt1 = qt0 + 32;

    floatx16 czero = {};
    floatx16 O0 = {}, O1 = {};
    float l0 = 0.f, l1 = 0.f;

    // loop-invariant theta B-fragments (hi lanes read the zero pad: K 8->16)
    Frag bth0, bth1;
    bth0.u = *(const uint4*)(lds + ((hi == 0) ? THETA_OFF + (qt0 + ln) * 16 : ZERO_OFF));
    bth1.u = *(const uint4*)(lds + ((hi == 0) ? THETA_OFF + (qt1 + ln) * 16 : ZERO_OFF));

    const char* gptr = lds + G_OFF + ln * G_ROW + hi * 16;
    const char* pptr = (hi == 0) ? (lds + PHI_OFF + ln * 16) : (lds + ZERO_OFF);
    const int   pstep = (hi == 0) ? 512 : 0;

    #pragma unroll 2
    for (int kb = 0; kb < 32; ++kb) {
        Frag aphi, gf0, gf1;
        aphi.u = *(const uint4*)(pptr);  pptr += pstep;
        gf0.u  = *(const uint4*)(gptr);
        gf1.u  = *(const uint4*)(gptr + 32);  gptr += 64;

        floatx16 S0 = __builtin_amdgcn_mfma_f32_32x32x16_bf16(aphi.s, bth0.s, czero, 0, 0, 0);
        floatx16 S1 = __builtin_amdgcn_mfma_f32_32x32x16_bf16(aphi.s, bth1.s, czero, 0, 0, 0);

        float p0[16], p1[16];
        #pragma unroll
        for (int r = 0; r < 16; ++r) { p0[r] = __builtin_amdgcn_exp2f(S0[r]); l0 += p0[r]; }
        #pragma unroll
        for (int r = 0; r < 16; ++r) { p1[r] = __builtin_amdgcn_exp2f(S1[r]); l1 += p1[r]; }

        Frag pa00, pa01, pa10, pa11;
        build_pfrags(p0, pa00, pa01);
        build_pfrags(p1, pa10, pa11);

        O0 = __builtin_amdgcn_mfma_f32_32x32x16_bf16(pa00.s, gf0.s, O0, 0, 0, 0);
        O0 = __builtin_amdgcn_mfma_f32_32x32x16_bf16(pa01.s, gf1.s, O0, 0, 0, 0);
        O1 = __builtin_amdgcn_mfma_f32_32x32x16_bf16(pa10.s, gf0.s, O1, 0, 0, 0);
        O1 = __builtin_amdgcn_mfma_f32_32x32x16_bf16(pa11.s, gf1.s, O1, 0, 0, 0);
    }

    // write unnormalized O to LDS (f32); rows = local q, cols = c (=ln)
    #pragma unroll
    for (int r = 0; r < 16; ++r) {
        const int rr = (r & 3) + 8 * (r >> 2) + 4 * hi;
        *(float*)(lds + ATTN_OFF + (qt0 + rr) * ATTN_ROW + ln * 4) = O0[r];
        *(float*)(lds + ATTN_OFF + (qt1 + rr) * ATTN_ROW + ln * 4) = O1[r];
    }
    const float l0t = l0 + __shfl_xor(l0, 32, 64);
    const float l1t = l1 + __shfl_xor(l1, 32, 64);
    __syncthreads();

    const float gam = gamma_p[0];

    // ---- epilogue: out = x + (gamma/l) * (w_o @ O) via MFMA ----
    #pragma unroll
    for (int tile = 0; tile < 2; ++tile) {
        const int   qt = tile ? qt1 : qt0;
        const float lt = tile ? l1t : l0t;
        const float gl = gam / lt;                    // lane ln == q of this tile

        // B-fragments: attn rows (f32 -> bf16), c-halves 0..15 / 16..31
        const char* ab = lds + ATTN_OFF + (qt + ln) * ATTN_ROW + hi * 32;
        const float4 a0 = *(const float4*)(ab);
        const float4 a1 = *(const float4*)(ab + 16);
        const float4 a2 = *(const float4*)(ab + 64);
        const float4 a3 = *(const float4*)(ab + 80);
        Frag bat0, bat1;
        bat0.u.x = cvt_pk_bf16(a0.x, a0.y); bat0.u.y = cvt_pk_bf16(a0.z, a0.w);
        bat0.u.z = cvt_pk_bf16(a1.x, a1.y); bat0.u.w = cvt_pk_bf16(a1.z, a1.w);
        bat1.u.x = cvt_pk_bf16(a2.x, a2.y); bat1.u.y = cvt_pk_bf16(a2.z, a2.w);
        bat1.u.z = cvt_pk_bf16(a3.x, a3.y); bat1.u.w = cvt_pk_bf16(a3.z, a3.w);

        // A-fragments: w_o, co-tiles 0/1 x c-halves 0/1
        const char* wb = lds + WO_OFF + ln * WO_ROW + hi * 16;
        Frag wa00, wa01, wa10, wa11;
        wa00.u = *(const uint4*)(wb);
        wa01.u = *(const uint4*)(wb + 32);
        wa10.u = *(const uint4*)(wb + 32 * WO_ROW);
        wa11.u = *(const uint4*)(wb + 32 * WO_ROW + 32);

        floatx16 D0 = __builtin_amdgcn_mfma_f32_32x32x16_bf16(wa00.s, bat0.s, czero, 0, 0, 0);
        D0 = __builtin_amdgcn_mfma_f32_32x32x16_bf16(wa01.s, bat1.s, D0, 0, 0, 0);
        floatx16 D1 = __builtin_amdgcn_mfma_f32_32x32x16_bf16(wa10.s, bat0.s, czero, 0, 0, 0);
        D1 = __builtin_amdgcn_mfma_f32_32x32x16_bf16(wa11.s, bat1.s, D1, 0, 0, 0);

        const int qg = qb0 + qt + ln;
        const float* xb = x   + (size_t)b * C_ * HW + qg;
        float*       ob = out + (size_t)b * C_ * HW + qg;
        #pragma unroll
        for (int r = 0; r < 16; ++r) {
            const int co = (r & 3) + 8 * (r >> 2) + 4 * hi;
            ob[(size_t)co * HW]        = xb[(size_t)co * HW]        + gl * D0[r];
            ob[(size_t)(co + 32) * HW] = xb[(size_t)(co + 32) * HW] + gl * D1[r];
        }
    }
}

extern "C" void kernel_launch(void* const* d_in, const int* in_sizes, int n_in,
                              void* d_out, int out_size, void* d_ws, size_t ws_size,
                              hipStream_t stream) {
    const float* x       = (const float*)d_in[0];
    const float* w_theta = (const float*)d_in[1];
    const float* w_phi   = (const float*)d_in[2];
    const float* w_g     = (const float*)d_in[3];
    const float* w_o     = (const float*)d_in[4];
    const float* gamma   = (const float*)d_in[5];
    float* out = (float*)d_out;

    __hip_bfloat16* phi_b = (__hip_bfloat16*)d_ws;                  // 16*1024*8  bf16 = 256 KB
    __hip_bfloat16* gT_b  = phi_b + (size_t)B_ * KP * 8;            // 16*32*1024 bf16 = 1 MB

    convpool_kernel<<<dim3(B_ * 16), dim3(256), 0, stream>>>(x, w_phi, w_g, phi_b, gT_b);
    attn_kernel<<<dim3(B_ * 16), dim3(256), 0, stream>>>(x, w_theta, w_o, gamma,
                                                         phi_b, gT_b, out);
}